// Round 9
// baseline (75.341 us; speedup 1.0000x reference)
//
#include <hip/hip_runtime.h>
#include <math.h>

#define D_MODEL 2048
#define NUM_EXP 64

typedef _Float16 f16x8 __attribute__((ext_vector_type(8)));
typedef float    f32x4 __attribute__((ext_vector_type(4)));

// ---------------------------------------------------------------------------
// k0: W[64][2048] fp32 -> fragment-linear f16 hi/lo (W = wh + wl*2^-12,
// wl scaled by 4096; both splits exact). Frag (kc, mf): lane l holds
// A[m = mf*16 + (l&15)][k = kc*32 + (l>>4)*8 + j], flat at whf[(kc*4+mf)*64+l]
// -> k1's W-load is a fully-coalesced 1KB wave read, L2-resident.
// ---------------------------------------------------------------------------
__global__ __launch_bounds__(256)
void k0_convw(const float* __restrict__ W, f16x8* __restrict__ whf,
              f16x8* __restrict__ wlf) {
    const int t    = blockIdx.x * 256 + threadIdx.x;
    const int lane = t & 63;
    const int mf   = (t >> 6) & 3;
    const int kc   = t >> 8;
    const int m    = mf * 16 + (lane & 15);
    const int k0   = kc * 32 + ((lane >> 4) << 3);
    const float* src = W + (size_t)m * D_MODEL + k0;
    f16x8 h, l;
#pragma unroll
    for (int j = 0; j < 8; ++j) {
        float v = src[j];
        _Float16 hh = (_Float16)v;
        h[j] = hh;
        l[j] = (_Float16)((v - (float)hh) * 4096.f);
    }
    whf[t] = h;
    wlf[t] = l;
}

// ---------------------------------------------------------------------------
// k1: reg-direct fused router, sized for register headroom (R6 failed via
// register starvation -> per-load serialization; acc here is 32 regs, not 128).
// Block = 4 waves = 32 tokens: wave w = (tf = w>>1 token-16-group,
// ks = w&1 K-half). Wave computes 16 tok x 64 exp x 1024 k: 32 chunks of
// 32-k, per chunk 8 W-frag loads + 2 x float4 loads -> 12 MFMAs (exact fp16
// split: logits = xh*wh + 2^-12 (xh*wl + xl*wh), low terms scaled 2^12).
// Manual named double-buffer; no barriers in the K-loop.
// Epilogue: 16KB swizzled LDS tile, 2-K-slice reduce, per-wave softmax +
// top-2 (lax.top_k tie rule: lower index wins), per-block expert partials.
// Grid: N/32 = 512 blocks; target 12 waves/CU via launch_bounds(256,3).
// ---------------------------------------------------------------------------
__global__ __launch_bounds__(256, 3)
void k1_fused(const float* __restrict__ x, const f16x8* __restrict__ whf,
              const f16x8* __restrict__ wlf, float* __restrict__ out,
              float* __restrict__ p_part, float* __restrict__ f_part, int N) {
    const int tid  = threadIdx.x;
    const int lane = tid & 63;
    const int w    = tid >> 6;        // 0..3
    const int tf   = w >> 1;          // token 16-group
    const int ks   = w & 1;           // K half
    const int tok0 = blockIdx.x * 32;

    const float* xrow = x + (size_t)(tok0 + tf * 16 + (lane & 15)) * D_MODEL
                      + ks * 1024 + ((lane >> 4) << 3);
    const f16x8* wb = whf + (size_t)(ks * 128) * 64 + lane;   // + (c*4+mf)*64
    const f16x8* lb = wlf + (size_t)(ks * 128) * 64 + lane;

    f32x4 acc1[4], acc2[4];
#pragma unroll
    for (int mf = 0; mf < 4; ++mf) {
        acc1[mf] = f32x4{0.f, 0.f, 0.f, 0.f};
        acc2[mf] = f32x4{0.f, 0.f, 0.f, 0.f};
    }

    f16x8 wh0[4], wl0[4], wh1[4], wl1[4];
    float4 a0, b0, a1, b1;

    auto LOAD = [&](int c, f16x8 (&wh)[4], f16x8 (&wl)[4], float4& xa, float4& xb) {
#pragma unroll
        for (int mf = 0; mf < 4; ++mf) {
            wh[mf] = wb[(c * 4 + mf) * 64];
            wl[mf] = lb[(c * 4 + mf) * 64];
        }
        xa = *(const float4*)(xrow + (size_t)c * 32);
        xb = *(const float4*)(xrow + (size_t)c * 32 + 4);
    };
    auto STEP = [&](const f16x8 (&wh)[4], const f16x8 (&wl)[4],
                    const float4 xa, const float4 xb) {
        const float v[8] = {xa.x, xa.y, xa.z, xa.w, xb.x, xb.y, xb.z, xb.w};
        f16x8 xh, xl;
#pragma unroll
        for (int j = 0; j < 8; ++j) {
            _Float16 h = (_Float16)v[j];
            xh[j] = h;
            xl[j] = (_Float16)((v[j] - (float)h) * 4096.f);
        }
#pragma unroll
        for (int mf = 0; mf < 4; ++mf) {
            acc1[mf] = __builtin_amdgcn_mfma_f32_16x16x32_f16(wh[mf], xh, acc1[mf], 0, 0, 0);
            acc2[mf] = __builtin_amdgcn_mfma_f32_16x16x32_f16(wh[mf], xl, acc2[mf], 0, 0, 0);
            acc2[mf] = __builtin_amdgcn_mfma_f32_16x16x32_f16(wl[mf], xh, acc2[mf], 0, 0, 0);
        }
    };

    LOAD(0, wh0, wl0, a0, b0);
#pragma unroll
    for (int c = 0; c < 32; c += 2) {
        if (c + 1 < 32) LOAD(c + 1, wh1, wl1, a1, b1);
        STEP(wh0, wl0, a0, b0);
        if (c + 2 < 32) LOAD(c + 2, wh0, wl0, a0, b0);
        if (c + 1 < 32) STEP(wh1, wl1, a1, b1);
    }

    // --- epilogue: swizzled LDS tile [w][16 tok][64 exp] -------------------
    // C layout: col = lane&15 = token, row = (lane>>4)*4 + p = expert.
    __shared__ float part[4 * 16 * 64];     // 16 KB
    __shared__ float p_red[4][64], f_red[4][64];

    const int ftok = lane & 15;
    const int fs   = lane >> 4;
#pragma unroll
    for (int mf = 0; mf < 4; ++mf) {
        f32x4 o = acc1[mf] + acc2[mf] * (1.f / 4096.f);
        const int e0 = mf * 16 + fs * 4;
        *(f32x4*)&part[(w * 16 + ftok) * 64 + (e0 ^ ((ftok & 7) << 2))] = o;
    }
    __syncthreads();

    // --- reduce 2 K-halves + softmax + top-2, 8 tokens per wave ------------
    float pacc = 0.f, facc = 0.f;
#pragma unroll
    for (int i = 0; i < 8; ++i) {
        const int tl  = w * 8 + i;          // 0..31
        const int g   = (tl >> 4) * 2;      // tf-group base
        const int row = tl & 15;
        const int col = lane ^ ((row & 7) << 2);
        float logit = part[(g * 16 + row) * 64 + col]
                    + part[((g + 1) * 16 + row) * 64 + col];

        float m = logit;
        for (int off = 32; off; off >>= 1) m = fmaxf(m, __shfl_xor(m, off));
        float p = __expf(logit - m);
        float S = p;
        for (int off = 32; off; off >>= 1) S += __shfl_xor(S, off);
        float prob = p / S;

        float bv = logit; int bi = lane;
        for (int off = 32; off; off >>= 1) {
            float ov = __shfl_xor(bv, off);
            int   oi = __shfl_xor(bi, off);
            if (ov > bv || (ov == bv && oi < bi)) { bv = ov; bi = oi; }
        }
        float cv = (lane == bi) ? -INFINITY : logit;
        int   ci = lane;
        for (int off = 32; off; off >>= 1) {
            float ov = __shfl_xor(cv, off);
            int   oi = __shfl_xor(ci, off);
            if (ov > cv || (ov == cv && oi < ci)) { cv = ov; ci = oi; }
        }

        if (lane == 0) {
            const int gt = tok0 + tl;
            float w0 = 1.f / (1.f + __expf(cv - bv));
            out[(size_t)gt * 2]     = w0;
            out[(size_t)gt * 2 + 1] = 1.f - w0;
            out[(size_t)2 * N + gt * 2]     = (float)bi;
            out[(size_t)2 * N + gt * 2 + 1] = (float)ci;
        }

        pacc += prob;
        facc += (lane == bi ? 1.f : 0.f) + (lane == ci ? 1.f : 0.f);
    }

    p_red[w][lane] = pacc;
    f_red[w][lane] = facc;
    __syncthreads();
    if (w == 0) {
        float sp = p_red[0][lane] + p_red[1][lane] + p_red[2][lane] + p_red[3][lane];
        float sf = f_red[0][lane] + f_red[1][lane] + f_red[2][lane] + f_red[3][lane];
        p_part[(size_t)blockIdx.x * NUM_EXP + lane] = sp;
        f_part[(size_t)blockIdx.x * NUM_EXP + lane] = sf;
    }
}

// ---------------------------------------------------------------------------
// k3: deterministic aux-loss reduction over per-block partials.
// aux = E * sum_i (f_sum_i / N) * (p_sum_i / N)
// ---------------------------------------------------------------------------
__global__ __launch_bounds__(1024)
void k3_aux(const float* __restrict__ p_part, const float* __restrict__ f_part,
            float* __restrict__ out, int N, int B2) {
    const int lane = threadIdx.x & 63;
    const int wid  = threadIdx.x >> 6;    // 0..15
    float sp = 0.f, sf = 0.f;
    for (int b = wid; b < B2; b += 16) {
        sp += p_part[(size_t)b * NUM_EXP + lane];
        sf += f_part[(size_t)b * NUM_EXP + lane];
    }
    __shared__ float lsp[16][64];
    __shared__ float lsf[16][64];
    lsp[wid][lane] = sp;
    lsf[wid][lane] = sf;
    __syncthreads();
    if (wid == 0) {
        float tsp = 0.f, tsf = 0.f;
#pragma unroll
        for (int w2 = 0; w2 < 16; ++w2) { tsp += lsp[w2][lane]; tsf += lsf[w2][lane]; }
        float v = tsp * tsf;
        for (int off = 32; off; off >>= 1) v += __shfl_xor(v, off);
        if (lane == 0)
            out[(size_t)4 * N] = (float)NUM_EXP * v / ((float)N * (float)N);
    }
}

extern "C" void kernel_launch(void* const* d_in, const int* in_sizes, int n_in,
                              void* d_out, int out_size, void* d_ws, size_t ws_size,
                              hipStream_t stream) {
    const float* x = (const float*)d_in[0];
    const float* W = (const float*)d_in[1];
    float* out = (float*)d_out;

    const int N  = in_sizes[0] / D_MODEL;   // 16384
    const int B1 = N / 32;                  // 512 blocks

    // ws: [whf 256KB][wlf 256KB][p_part 128KB][f_part 128KB]
    f16x8* whf = (f16x8*)d_ws;
    f16x8* wlf = whf + 16384;
    float* p_part = (float*)(wlf + 16384);
    float* f_part = p_part + (size_t)B1 * NUM_EXP;

    k0_convw<<<64, 256, 0, stream>>>(W, whf, wlf);
    k1_fused<<<B1, 256, 0, stream>>>(x, whf, wlf, out, p_part, f_part, N);
    k3_aux<<<1, 1024, 0, stream>>>(p_part, f_part, out, N, B1);
}

// Round 10
// 51.908 us; speedup vs baseline: 1.4514x; 1.4514x over previous
//
#include <hip/hip_runtime.h>
#include <math.h>

#define D_MODEL 2048
#define NUM_EXP 64
#define TOKB    32
#define BK      64
#define STEPS   32

typedef _Float16 f16x4 __attribute__((ext_vector_type(4)));
typedef _Float16 f16x8 __attribute__((ext_vector_type(8)));
typedef float    f32x4 __attribute__((ext_vector_type(4)));

// ---------------------------------------------------------------------------
// k0: W[64][2048] fp32 -> fragment-linear f16 hi/lo (W = wh + wl*2^-12,
// wl scaled by 4096; split exact). Frag (kc, mf): lane l holds
// A[m = mf*16 + (l&15)][k = kc*32 + (l>>4)*8 + j], flat at whf[(kc*4+mf)*64+l].
// ---------------------------------------------------------------------------
__global__ __launch_bounds__(256)
void k0_convw(const float* __restrict__ W, f16x8* __restrict__ whf,
              f16x8* __restrict__ wlf) {
    const int t    = blockIdx.x * 256 + threadIdx.x;
    const int lane = t & 63;
    const int mf   = (t >> 6) & 3;
    const int kc   = t >> 8;
    const int m    = mf * 16 + (lane & 15);
    const int k0   = kc * 32 + ((lane >> 4) << 3);
    const float* src = W + (size_t)m * D_MODEL + k0;
    f16x8 h, l;
#pragma unroll
    for (int j = 0; j < 8; ++j) {
        float v = src[j];
        _Float16 hh = (_Float16)v;
        h[j] = hh;
        l[j] = (_Float16)((v - (float)hh) * 4096.f);
    }
    whf[t] = h;
    wlf[t] = l;
}

// ---------------------------------------------------------------------------
// k1: R7 structure + (a) per-block K-phase rotation, (b) T14 async-stage.
// Block = 512 thr (8 waves) = 32 tokens x 64 experts x full K; wave wid owns
// frag (tf = wid&1, mf = wid>>1), ONE acc pair, full-K accumulate.
// Step order per block: sp = (i + blockIdx.x) & 31  -> at any instant the
// grid's x reads cover the full 8KB row (not one 256B column) and W reads
// spread over all 32 step-addresses (no single hot L2/L3 slice).
// Per step: GLOAD(sp+1) into regs -> sched_barrier(0) (pin: no sinking) ->
// COMPUTE(buf) from LDS -> SWRITE(sp+1 -> other buf) -> one barrier.
// fp32->f16 hi/lo cvt once per element at SWRITE. Deterministic fixed-order
// sums; rotation only permutes the per-token chunk order (fp32 noise well
// under threshold). Epilogue: ep tile -> per-wave softmax + top-2 (lower
// index wins) + per-block expert partials. LDS 60KB -> 2 blocks/CU.
// ---------------------------------------------------------------------------
__global__ __launch_bounds__(512, 4)
void k1_fused(const float* __restrict__ x, const f16x8* __restrict__ whf,
              const f16x8* __restrict__ wlf, float* __restrict__ out,
              float* __restrict__ p_part, float* __restrict__ f_part, int N) {
    const int tid  = threadIdx.x;
    const int lane = tid & 63;
    const int wid  = tid >> 6;          // 0..7
    const int tok0 = blockIdx.x * TOKB;
    const int tf   = wid & 1;
    const int mf   = wid >> 1;

    __shared__ _Float16 xh_s[2][TOKB][BK];      // 8 KB
    __shared__ _Float16 xl_s[2][TOKB][BK];      // 8 KB
    __shared__ f16x8    w_s[2][2][512];         // 32 KB
    __shared__ float    ep[TOKB][NUM_EXP];      // 8 KB
    __shared__ float    p_red[8][64], f_red[8][64];

    // x staging map: row = tid>>4, 16 threads x 16B contiguous per row.
    const int srow = tid >> 4;
    const int sc4  = tid & 15;
    const float* xsrc = x + (size_t)(tok0 + srow) * D_MODEL + sc4 * 4;
    const int    ko   = (sc4 * 8) ^ ((srow & 7) << 4);   // swizzled byte off

    f32x4 acc1 = f32x4{0.f, 0.f, 0.f, 0.f};
    f32x4 acc2 = f32x4{0.f, 0.f, 0.f, 0.f};

    float4 xv; f16x8 wv, lv;                    // in-flight stage registers
    auto GLOAD = [&](int s) {
        xv = *(const float4*)(xsrc + (size_t)s * BK);
        wv = whf[(size_t)(2 * s) * 256 + tid];
        lv = wlf[(size_t)(2 * s) * 256 + tid];
    };
    auto SWRITE = [&](int buf) {
        const float vf[4] = {xv.x, xv.y, xv.z, xv.w};
        f16x4 h, l;
#pragma unroll
        for (int j = 0; j < 4; ++j) {
            _Float16 hh = (_Float16)vf[j];
            h[j] = hh;
            l[j] = (_Float16)((vf[j] - (float)hh) * 4096.f);
        }
        *(f16x4*)((char*)&xh_s[buf][srow][0] + ko) = h;
        *(f16x4*)((char*)&xl_s[buf][srow][0] + ko) = l;
        w_s[buf][0][tid] = wv;
        w_s[buf][1][tid] = lv;
    };

    const int ft = lane & 15;
    const int fs = lane >> 4;
    auto COMPUTE = [&](int buf) {
        const char* xhb = (const char*)&xh_s[buf][tf * 16 + ft][0];
        const char* xlb = (const char*)&xl_s[buf][tf * 16 + ft][0];
#pragma unroll
        for (int c = 0; c < 2; ++c) {
            const int o = (c * 64 + fs * 16) ^ ((ft & 7) << 4);
            const f16x8 xh = *(const f16x8*)(xhb + o);
            const f16x8 xl = *(const f16x8*)(xlb + o);
            const f16x8 wh = w_s[buf][0][c * 256 + mf * 64 + lane];
            const f16x8 wl = w_s[buf][1][c * 256 + mf * 64 + lane];
            acc1 = __builtin_amdgcn_mfma_f32_16x16x32_f16(wh, xh, acc1, 0, 0, 0);
            acc2 = __builtin_amdgcn_mfma_f32_16x16x32_f16(wh, xl, acc2, 0, 0, 0);
            acc2 = __builtin_amdgcn_mfma_f32_16x16x32_f16(wl, xh, acc2, 0, 0, 0);
        }
    };

    // --- pipelined K loop with per-block phase rotation --------------------
    int sp = blockIdx.x & 31;                   // this block's step order
    GLOAD(sp);
    SWRITE(0);
    __syncthreads();
#pragma unroll 2
    for (int i = 0; i < STEPS; ++i) {
        const int spn = (sp + 1) & 31;
        if (i + 1 < STEPS) GLOAD(spn);
        __builtin_amdgcn_sched_barrier(0);      // pin loads above compute
        COMPUTE(i & 1);
        if (i + 1 < STEPS) SWRITE((i + 1) & 1);
        __syncthreads();
        sp = spn;
    }

    // --- epilogue: logits tile (C: col=lane&15=token, row=(lane>>4)*4+p) ---
    {
        f32x4 o = acc1 + acc2 * (1.f / 4096.f);
        *(f32x4*)&ep[tf * 16 + ft][mf * 16 + fs * 4] = o;
    }
    __syncthreads();

    // --- softmax + top-2, 4 tokens per wave (lane == expert) ---------------
    float pacc = 0.f, facc = 0.f;
#pragma unroll
    for (int i = 0; i < 4; ++i) {
        const int tl = wid * 4 + i;
        float logit = ep[tl][lane];

        float m = logit;
        for (int off = 32; off; off >>= 1) m = fmaxf(m, __shfl_xor(m, off));
        float p = __expf(logit - m);
        float S = p;
        for (int off = 32; off; off >>= 1) S += __shfl_xor(S, off);
        float prob = p / S;

        float bv = logit; int bi = lane;
        for (int off = 32; off; off >>= 1) {
            float ov = __shfl_xor(bv, off);
            int   oi = __shfl_xor(bi, off);
            if (ov > bv || (ov == bv && oi < bi)) { bv = ov; bi = oi; }
        }
        float cv = (lane == bi) ? -INFINITY : logit;
        int   ci = lane;
        for (int off = 32; off; off >>= 1) {
            float ov = __shfl_xor(cv, off);
            int   oi = __shfl_xor(ci, off);
            if (ov > cv || (ov == cv && oi < ci)) { cv = ov; ci = oi; }
        }

        if (lane == 0) {
            const int gt = tok0 + tl;
            float w0 = 1.f / (1.f + __expf(cv - bv));
            out[(size_t)gt * 2]     = w0;
            out[(size_t)gt * 2 + 1] = 1.f - w0;
            out[(size_t)2 * N + gt * 2]     = (float)bi;
            out[(size_t)2 * N + gt * 2 + 1] = (float)ci;
        }

        pacc += prob;
        facc += (lane == bi ? 1.f : 0.f) + (lane == ci ? 1.f : 0.f);
    }

    p_red[wid][lane] = pacc;
    f_red[wid][lane] = facc;
    __syncthreads();
    if (wid == 0) {
        float sp2 = 0.f, sf2 = 0.f;
#pragma unroll
        for (int w = 0; w < 8; ++w) { sp2 += p_red[w][lane]; sf2 += f_red[w][lane]; }
        p_part[(size_t)blockIdx.x * NUM_EXP + lane] = sp2;
        f_part[(size_t)blockIdx.x * NUM_EXP + lane] = sf2;
    }
}

// ---------------------------------------------------------------------------
// k3: deterministic aux-loss reduction over per-block partials.
// aux = E * sum_i (f_sum_i / N) * (p_sum_i / N)
// ---------------------------------------------------------------------------
__global__ __launch_bounds__(1024)
void k3_aux(const float* __restrict__ p_part, const float* __restrict__ f_part,
            float* __restrict__ out, int N, int B2) {
    const int lane = threadIdx.x & 63;
    const int wid  = threadIdx.x >> 6;    // 0..15
    float sp = 0.f, sf = 0.f;
    for (int b = wid; b < B2; b += 16) {
        sp += p_part[(size_t)b * NUM_EXP + lane];
        sf += f_part[(size_t)b * NUM_EXP + lane];
    }
    __shared__ float lsp[16][64];
    __shared__ float lsf[16][64];
    lsp[wid][lane] = sp;
    lsf[wid][lane] = sf;
    __syncthreads();
    if (wid == 0) {
        float tsp = 0.f, tsf = 0.f;
#pragma unroll
        for (int w2 = 0; w2 < 16; ++w2) { tsp += lsp[w2][lane]; tsf += lsf[w2][lane]; }
        float v = tsp * tsf;
        for (int off = 32; off; off >>= 1) v += __shfl_xor(v, off);
        if (lane == 0)
            out[(size_t)4 * N] = (float)NUM_EXP * v / ((float)N * (float)N);
    }
}

extern "C" void kernel_launch(void* const* d_in, const int* in_sizes, int n_in,
                              void* d_out, int out_size, void* d_ws, size_t ws_size,
                              hipStream_t stream) {
    const float* x = (const float*)d_in[0];
    const float* W = (const float*)d_in[1];
    float* out = (float*)d_out;

    const int N  = in_sizes[0] / D_MODEL;   // 16384
    const int B1 = N / TOKB;                // 512 blocks

    // ws: [whf 256KB][wlf 256KB][p_part 128KB][f_part 128KB]
    f16x8* whf = (f16x8*)d_ws;
    f16x8* wlf = whf + 16384;
    float* p_part = (float*)(wlf + 16384);
    float* f_part = p_part + (size_t)B1 * NUM_EXP;

    k0_convw<<<64, 256, 0, stream>>>(W, whf, wlf);
    k1_fused<<<B1, 512, 0, stream>>>(x, whf, wlf, out, p_part, f_part, N);
    k3_aux<<<1, 1024, 0, stream>>>(p_part, f_part, out, N, B1);
}